// Round 2
// baseline (238.367 us; speedup 1.0000x reference)
//
#include <hip/hip_runtime.h>

#define DD 128   // feature dim, fixed by the reference

// Per-element update: z = x*a + c; z2 = z*z; p *= (1 - z2); s += z2.  (4 VALU ops)
#define UPD4(P, S, XV)                                                          \
    {                                                                           \
        float z, z2;                                                            \
        z = fmaf((XV).x, av.x, cv.x); z2 = z * z; P = fmaf(-z2, P, P); S += z2; \
        z = fmaf((XV).y, av.y, cv.y); z2 = z * z; P = fmaf(-z2, P, P); S += z2; \
        z = fmaf((XV).z, av.z, cv.z); z2 = z * z; P = fmaf(-z2, P, P); S += z2; \
        z = fmaf((XV).w, av.w, cv.w); z2 = z * z; P = fmaf(-z2, P, P); S += z2; \
    }

// LDS layout (per 64-d phase):
//   a_s/c_s: [64 rows][24 quads]; quads 0..15 hold the row's 16 d-quads,
//            quads 16..23 replicate quads 0..7. Compute reads row r at
//            slot (lane&7)+q  -> per-thread base + compile-time offset,
//            8 consecutive slots across lanes -> all 32 banks, no conflict,
//            and NO per-read address math (q folds into ds_read offset imm).
//   x_s:     [32 rows][16 quads], read wave-uniform -> LDS broadcast (free).
__global__ __launch_bounds__(512, 4)
void wavelet_prod_kernel(const float* __restrict__ x,
                         const float* __restrict__ bias,
                         const float* __restrict__ scale,
                         float* __restrict__ out,
                         int B, int N)
{
    __shared__ float4 a_s[64 * 24];
    __shared__ float4 c_s[64 * 24];
    __shared__ float4 x_s[32 * 16];

    const int tid  = threadIdx.x;
    const int lane = tid & 63;
    const int wave = tid >> 6;

    const int n0 = blockIdx.x * 64;   // 64 n per block (one per lane)
    const int bb = blockIdx.y * 32;   // 32 b per block (4 per wave)

    const float4* arow = a_s + lane * 24 + (lane & 7);
    const float4* crow = c_s + lane * 24 + (lane & 7);

    float p0 = 1.f, p1 = 1.f, p2 = 1.f, p3 = 1.f;
    float s0 = 0.f, s1 = 0.f, s2 = 0.f, s3 = 0.f;

    const float kexp = -0.7213475204444817f;  // -0.5 * log2(e)

    #pragma unroll
    for (int ph = 0; ph < 2; ++ph) {          // two 64-d phases
        if (ph) __syncthreads();              // drain previous phase's readers

        // ---- stage a = 1/scale, c = -bias/scale (64 n x 64 d) ----
        {
            const float4* b4 = (const float4*)bias;
            const float4* s4 = (const float4*)scale;
            #pragma unroll
            for (int k = 0; k < 2; ++k) {
                int flat = tid + k * 512;     // 0..1023
                int r = flat >> 4;            // row 0..63
                int q = flat & 15;            // d-quad 0..15
                int src = (n0 + r) * 32 + ph * 16 + q;
                float4 sv = s4[src];
                float4 bv = b4[src];
                float4 av, cv;
                av.x = 1.0f / sv.x; av.y = 1.0f / sv.y;
                av.z = 1.0f / sv.z; av.w = 1.0f / sv.w;
                cv.x = -bv.x * av.x; cv.y = -bv.y * av.y;
                cv.z = -bv.z * av.z; cv.w = -bv.w * av.w;
                a_s[r * 24 + q] = av;
                c_s[r * 24 + q] = cv;
                if (q < 8) {                  // replicate for additive swizzle
                    a_s[r * 24 + 16 + q] = av;
                    c_s[r * 24 + 16 + q] = cv;
                }
            }
            // ---- stage x tile (32 b x 64 d), linear ----
            int r = tid >> 4, q = tid & 15;
            x_s[tid] = ((const float4*)x)[(bb + r) * 32 + ph * 16 + q];
        }
        __syncthreads();

        const float4* xr0 = x_s + (wave * 4 + 0) * 16;
        const float4* xr1 = x_s + (wave * 4 + 1) * 16;
        const float4* xr2 = x_s + (wave * 4 + 2) * 16;
        const float4* xr3 = x_s + (wave * 4 + 3) * 16;

        #pragma unroll
        for (int f = 0; f < 4; ++f) {         // 4 folds of 16 d per phase
            #pragma unroll
            for (int cc = 0; cc < 4; ++cc) {
                const int q = f * 4 + cc;
                float4 av = arow[q];          // swizzled via base, imm offset
                float4 cv = crow[q];
                float4 x0 = xr0[q];           // uniform -> broadcast
                float4 x1 = xr1[q];
                float4 x2 = xr2[q];
                float4 x3 = xr3[q];
                UPD4(p0, s0, x0);
                UPD4(p1, s1, x1);
                UPD4(p2, s2, x2);
                UPD4(p3, s3, x3);
            }
            // fold Gaussian factor every 16 d (keeps p in f32 range)
            p0 *= __builtin_amdgcn_exp2f(s0 * kexp); s0 = 0.f;
            p1 *= __builtin_amdgcn_exp2f(s1 * kexp); s1 = 0.f;
            p2 *= __builtin_amdgcn_exp2f(s2 * kexp); s2 = 0.f;
            p3 *= __builtin_amdgcn_exp2f(s3 * kexp); s3 = 0.f;
        }
    }

    float* o = out + (size_t)(bb + wave * 4) * N + n0 + lane;
    o[0 * N] = p0;
    o[1 * N] = p1;
    o[2 * N] = p2;
    o[3 * N] = p3;
}

extern "C" void kernel_launch(void* const* d_in, const int* in_sizes, int n_in,
                              void* d_out, int out_size, void* d_ws, size_t ws_size,
                              hipStream_t stream)
{
    const float* x     = (const float*)d_in[0];
    const float* bias  = (const float*)d_in[1];
    const float* scale = (const float*)d_in[2];
    float* out = (float*)d_out;

    const int B = in_sizes[0] / DD;   // 2048
    const int N = in_sizes[1] / DD;   // 512

    dim3 grid(N / 64, B / 32);        // (8, 64) = 512 blocks
    wavelet_prod_kernel<<<grid, 512, 0, stream>>>(x, bias, scale, out, B, N);
}

// Round 3
// 22.899 us; speedup vs baseline: 10.4095x; 10.4095x over previous
//
#include <hip/hip_runtime.h>

#define DD 128   // feature dim, fixed by the reference

typedef float v2f __attribute__((ext_vector_type(2)));
typedef float v4f __attribute__((ext_vector_type(4)));

// Packed per-pair update: z = x*a + c; zz = z*z; p *= (1 - zz); s += zz.
// 4 VOP3P instructions (v_pk_fma_f32 / v_pk_mul_f32 / v_pk_fma_f32(neg) / v_pk_add_f32).
#define UPD2(P, S, XX, AA, CC)                                   \
    {                                                            \
        v2f z  = __builtin_elementwise_fma((XX), (AA), (CC));    \
        v2f zz = z * z;                                          \
        P = __builtin_elementwise_fma(-zz, P, P);                \
        S += zz;                                                 \
    }

__global__ __launch_bounds__(512, 4)
void wavelet_prod_kernel(const float* __restrict__ x,
                         const float* __restrict__ bias,
                         const float* __restrict__ scale,
                         float* __restrict__ out,
                         int B, int N)
{
    // a = 1/scale, c = -bias/scale for this block's 64 n-rows, full D=128.
    // [64 rows][32 quads], quad index XOR-swizzled by (row&7): compute-phase
    // read (all lanes same q, different rows) spreads across banks at the
    // b128 wave64 minimum (8 words/bank). Identical to the R1 layout.
    __shared__ v4f a_s[64 * 32];
    __shared__ v4f c_s[64 * 32];

    const int tid  = threadIdx.x;
    const int lane = tid & 63;
    const int wave = tid >> 6;

    const int n0 = blockIdx.x * 64;   // 64 n per block (one per lane)
    const int bb = blockIdx.y * 32;   // 32 b per block (4 per wave)

    // ---- one-time staging: 64x128 bias/scale tile -> a,c in LDS ----
    {
        const v4f* b4 = (const v4f*)(bias  + (size_t)n0 * DD);
        const v4f* s4 = (const v4f*)(scale + (size_t)n0 * DD);
        #pragma unroll
        for (int k = 0; k < 4; ++k) {
            int flat = tid + k * 512;          // 0..2047 float4 slots
            int r = flat >> 5;                 // row within tile (0..63)
            int q = flat & 31;                 // d-quad (0..31)
            v4f sv = s4[flat];
            v4f bv = b4[flat];
            v4f av, cv;
            av.x = 1.0f / sv.x; av.y = 1.0f / sv.y;
            av.z = 1.0f / sv.z; av.w = 1.0f / sv.w;
            cv = -bv * av;
            int dst = r * 32 + (q ^ (r & 7));
            a_s[dst] = av;
            c_s[dst] = cv;
        }
    }
    __syncthreads();

    const int brow = bb + wave * 4;
    const v4f* xr = (const v4f*)(x + (size_t)brow * DD);  // rows stride 32 quads

    const v4f* arow = a_s + lane * 32;
    const v4f* crow = c_s + lane * 32;
    const int sw = lane & 7;

    // Two independent packed product/sum chains per b-row, merged each fold.
    v2f p0 = {1.f, 1.f}, p1 = {1.f, 1.f}, p2 = {1.f, 1.f}, p3 = {1.f, 1.f};
    v2f s0 = {0.f, 0.f}, s1 = {0.f, 0.f}, s2 = {0.f, 0.f}, s3 = {0.f, 0.f};

    const float kexp = -0.7213475204444817f;  // -0.5 * log2(e)

    #pragma unroll
    for (int f = 0; f < 8; ++f) {             // 8 folds of 16 d
        #pragma unroll
        for (int cc = 0; cc < 4; ++cc) {      // 4 quads of 4 d
            const int q    = f * 4 + cc;
            const int slot = q ^ sw;          // one xor, shared by a & c
            v4f av = arow[slot];
            v4f cv = crow[slot];
            v4f x0 = xr[q];
            v4f x1 = xr[32 + q];
            v4f x2 = xr[64 + q];
            v4f x3 = xr[96 + q];
            UPD2(p0, s0, x0.lo, av.lo, cv.lo);
            UPD2(p0, s0, x0.hi, av.hi, cv.hi);
            UPD2(p1, s1, x1.lo, av.lo, cv.lo);
            UPD2(p1, s1, x1.hi, av.hi, cv.hi);
            UPD2(p2, s2, x2.lo, av.lo, cv.lo);
            UPD2(p2, s2, x2.hi, av.hi, cv.hi);
            UPD2(p3, s3, x3.lo, av.lo, cv.lo);
            UPD2(p3, s3, x3.hi, av.hi, cv.hi);
        }
        // Fold Gaussian factor + merge the two chains every 16 d: keeps the
        // raw partial products bounded (<= 8 factors per chain per window).
        p0.x = p0.x * p0.y * __builtin_amdgcn_exp2f((s0.x + s0.y) * kexp);
        p0.y = 1.f; s0 = (v2f){0.f, 0.f};
        p1.x = p1.x * p1.y * __builtin_amdgcn_exp2f((s1.x + s1.y) * kexp);
        p1.y = 1.f; s1 = (v2f){0.f, 0.f};
        p2.x = p2.x * p2.y * __builtin_amdgcn_exp2f((s2.x + s2.y) * kexp);
        p2.y = 1.f; s2 = (v2f){0.f, 0.f};
        p3.x = p3.x * p3.y * __builtin_amdgcn_exp2f((s3.x + s3.y) * kexp);
        p3.y = 1.f; s3 = (v2f){0.f, 0.f};
    }

    float* o = out + (size_t)brow * N + n0 + lane;
    o[0 * N] = p0.x;
    o[1 * N] = p1.x;
    o[2 * N] = p2.x;
    o[3 * N] = p3.x;
}

extern "C" void kernel_launch(void* const* d_in, const int* in_sizes, int n_in,
                              void* d_out, int out_size, void* d_ws, size_t ws_size,
                              hipStream_t stream)
{
    const float* x     = (const float*)d_in[0];
    const float* bias  = (const float*)d_in[1];
    const float* scale = (const float*)d_in[2];
    float* out = (float*)d_out;

    const int B = in_sizes[0] / DD;   // 2048
    const int N = in_sizes[1] / DD;   // 512

    dim3 grid(N / 64, B / 32);        // (8, 64) = 512 blocks
    wavelet_prod_kernel<<<grid, 512, 0, stream>>>(x, bias, scale, out, B, N);
}